// Round 2
// baseline (123.413 us; speedup 1.0000x reference)
//
#include <hip/hip_runtime.h>
#include <math.h>

#define BB 4
#define PP 24
#define NN 3072
#define SS 128
#define CHUNK 512
#define NSPLIT 6             // NN / CHUNK
#define GRID (BB * PP * NSPLIT)   // 576
#define FINF 3.4e38f

// ws layout (floats):
//   [0, 96*128*8)                : per-(bp,s) split mins, 8 floats each (splits 0..5 + 2 pad)
//   [SCAL_F, SCAL_F + 96*6*4)    : per-(bp,split) scalars {pcl, cub, asum, pad}
//   [CNT_F]                      : completion counter (zeroed by superdec_zero each launch)
#define SCAL_F (96 * 128 * 8)
#define CNT_F  (SCAL_F + 96 * 6 * 4)

__device__ __forceinline__ float fexp_f(float v, float p) {
    float m = powf(fabsf(v), p);
    float s = (v > 0.f) ? 1.f : ((v < 0.f) ? -1.f : 0.f);
    return s * m;
}
__device__ __forceinline__ float fix_f(float v) {
    return ((v > 0.f) ? 1.f : -1.f) * fmaxf(fabsf(v), 1e-6f);
}
__device__ __forceinline__ float wave_sum(float v) {
    #pragma unroll
    for (int off = 32; off > 0; off >>= 1) v += __shfl_down(v, off);
    return v;
}
__device__ __forceinline__ float cub_dist(float px, float py, float pz,
                                          float nx, float ny, float nz,
                                          float sc0, float sc1, float sc2) {
    // argmax over {-nx,nx,-ny,ny,-nz,nz}; strict > == jnp first-max rule
    float best = -nx; int idx = 0;
    if ( nx > best) { best =  nx; idx = 1; }
    if (-ny > best) { best = -ny; idx = 2; }
    if ( ny > best) { best =  ny; idx = 3; }
    if (-nz > best) { best = -nz; idx = 4; }
    if ( nz > best) { best =  nz; idx = 5; }
    const int c = idx >> 1;
    const float scc = (c == 0) ? sc0 : ((c == 1) ? sc1 : sc2);
    const float fv  = (idx & 1) ? scc : -scc;
    float pr0 = (c == 0) ? fv : fminf(fmaxf(px, -sc0), sc0);
    float pr1 = (c == 1) ? fv : fminf(fmaxf(py, -sc1), sc1);
    float pr2 = (c == 2) ? fv : fminf(fmaxf(pz, -sc2), sc2);
    float d0 = pr0 - px, d1 = pr1 - py, d2 = pr2 - pz;
    return fmaf(d0, d0, fmaf(d1, d1, d2 * d2));
}

// ---- counter zeroing: plain kernel node (graph-capture-safe, unlike memset) ----
__global__ void superdec_zero(float* __restrict__ ws) {
    *(unsigned int*)(ws + CNT_F) = 0u;
}

// ---- Fused kernel: 576 blocks x 256 threads; last-finishing block does the
// ---- final reduction (counter at ws[CNT_F]).
__global__ __launch_bounds__(256) void superdec_fused(
    const float* __restrict__ pc, const float* __restrict__ nrm,
    const float* __restrict__ scale, const float* __restrict__ shape,
    const float* __restrict__ exist, const float* __restrict__ assign,
    const float* __restrict__ etas, const float* __restrict__ omegas,
    float* __restrict__ ws, float* __restrict__ out)
{
    const int blk   = blockIdx.x;
    const int bp    = blk / NSPLIT;
    const int split = blk % NSPLIT;
    const int b     = bp / PP;
    const int p     = bp % PP;
    const int tid   = threadIdx.x;
    const int n0    = split * CHUNK;
    const int pid   = tid & 127;   // point-group id: points pid*4 .. pid*4+3
    const int q     = tid >> 7;    // s-half: 0 -> s[0,64), 1 -> s[64,128)

    __shared__ float4 Xs[SS];          // (-2x, -2y, -2z, |x|^2)
    __shared__ float4 Pts[CHUNK];      // ( x,   y,   z,  |p|^2)
    __shared__ float4 dmin2[2][128];   // per (half, pid): 4 per-point d_eff mins
    __shared__ float  red[8 * SS];     // pass-B replica mins; reused by finisher
    __shared__ float  wsum[6];
    __shared__ unsigned int s_flag;

    const float sc0 = scale[bp * 3 + 0];
    const float sc1 = scale[bp * 3 + 1];
    const float sc2 = scale[bp * 3 + 2];

    // ---- load this thread's 4 points via 3 contiguous float4 loads ----
    const float4* pc4 = (const float4*)(pc + ((size_t)bp * NN + n0) * 3);
    const float4 g0 = pc4[pid * 3 + 0];
    const float4 g1 = pc4[pid * 3 + 1];
    const float4 g2 = pc4[pid * 3 + 2];
    const float px0 = g0.x, py0 = g0.y, pz0 = g0.z;
    const float px1 = g0.w, py1 = g1.x, pz1 = g1.y;
    const float px2 = g1.z, py2 = g1.w, pz2 = g2.x;
    const float px3 = g2.y, py3 = g2.z, pz3 = g2.w;
    const float ps0 = fmaf(px0, px0, fmaf(py0, py0, pz0 * pz0));
    const float ps1 = fmaf(px1, px1, fmaf(py1, py1, pz1 * pz1));
    const float ps2 = fmaf(px2, px2, fmaf(py2, py2, pz2 * pz2));
    const float ps3 = fmaf(px3, px3, fmaf(py3, py3, pz3 * pz3));

    float cub0 = 0.f, cub1 = 0.f, cub2 = 0.f, cub3 = 0.f;
    float am0 = 0.f, am1 = 0.f, am2 = 0.f, am3 = 0.f;

    if (q == 0) {
        // superquadric samples (1 per thread)
        {
            const float e1 = shape[bp * 2 + 0];
            const float e2 = shape[bp * 2 + 1];
            float eta = etas[bp * SS + tid];
            float omg = omegas[bp * SS + tid];
            eta = (eta == 0.f) ? 1e-6f : eta;
            omg = (omg == 0.f) ? 1e-6f : omg;
            float ce = cosf(eta), se = sinf(eta);
            float co = cosf(omg), so = sinf(omg);
            float fce = fexp_f(ce, e1);
            float x = fix_f(sc0 * fce * fexp_f(co, e2));
            float y = fix_f(sc1 * fce * fexp_f(so, e2));
            float z = fix_f(sc2 * fexp_f(se, e1));
            float xsq = fmaf(x, x, fmaf(y, y, z * z));
            Xs[tid] = make_float4(-2.f * x, -2.f * y, -2.f * z, xsq);
        }
        // stage points for pass B
        Pts[pid * 4 + 0] = make_float4(px0, py0, pz0, ps0);
        Pts[pid * 4 + 1] = make_float4(px1, py1, pz1, ps1);
        Pts[pid * 4 + 2] = make_float4(px2, py2, pz2, ps2);
        Pts[pid * 4 + 3] = make_float4(px3, py3, pz3, ps3);
        // cuboid terms (normals used once; only half-0 loads them)
        const float4* nr4 = (const float4*)(nrm + ((size_t)bp * NN + n0) * 3);
        const float4 h0 = nr4[pid * 3 + 0];
        const float4 h1 = nr4[pid * 3 + 1];
        const float4 h2 = nr4[pid * 3 + 2];
        cub0 = cub_dist(px0, py0, pz0, h0.x, h0.y, h0.z, sc0, sc1, sc2);
        cub1 = cub_dist(px1, py1, pz1, h0.w, h1.x, h1.y, sc0, sc1, sc2);
        cub2 = cub_dist(px2, py2, pz2, h1.z, h1.w, h2.x, sc0, sc1, sc2);
        cub3 = cub_dist(px3, py3, pz3, h2.y, h2.z, h2.w, sc0, sc1, sc2);
        const size_t abase = ((size_t)b * NN + n0 + pid * 4) * PP + p;
        am0 = assign[abase + 0 * PP];
        am1 = assign[abase + 1 * PP];
        am2 = assign[abase + 2 * PP];
        am3 = assign[abase + 3 * PP];
    }
    __syncthreads();

    // ---- Pass A: min over this half's 64 s for 4 points (d_eff = |x|^2-2x.p) ----
    {
        const int sb = q * 64;
        float m0 = FINF, m1 = FINF, m2 = FINF, m3 = FINF;
        #pragma unroll 4
        for (int s = 0; s < 64; s += 2) {
            float4 xa = Xs[sb + s];
            float4 xb = Xs[sb + s + 1];
            float d;
            d = fmaf(xa.x, px0, fmaf(xa.y, py0, fmaf(xa.z, pz0, xa.w))); m0 = fminf(m0, d);
            d = fmaf(xa.x, px1, fmaf(xa.y, py1, fmaf(xa.z, pz1, xa.w))); m1 = fminf(m1, d);
            d = fmaf(xa.x, px2, fmaf(xa.y, py2, fmaf(xa.z, pz2, xa.w))); m2 = fminf(m2, d);
            d = fmaf(xa.x, px3, fmaf(xa.y, py3, fmaf(xa.z, pz3, xa.w))); m3 = fminf(m3, d);
            d = fmaf(xb.x, px0, fmaf(xb.y, py0, fmaf(xb.z, pz0, xb.w))); m0 = fminf(m0, d);
            d = fmaf(xb.x, px1, fmaf(xb.y, py1, fmaf(xb.z, pz1, xb.w))); m1 = fminf(m1, d);
            d = fmaf(xb.x, px2, fmaf(xb.y, py2, fmaf(xb.z, pz2, xb.w))); m2 = fminf(m2, d);
            d = fmaf(xb.x, px3, fmaf(xb.y, py3, fmaf(xb.z, pz3, xb.w))); m3 = fminf(m3, d);
        }
        dmin2[q][pid] = make_float4(m0, m1, m2, m3);
    }
    __syncthreads();

    // ---- half-0: combine s-halves, weight, wave-sum scalars ----
    if (q == 0) {
        float4 a = dmin2[0][pid];
        float4 c = dmin2[1][pid];
        float d0 = fminf(a.x, c.x) + ps0;
        float d1 = fminf(a.y, c.y) + ps1;
        float d2 = fminf(a.z, c.z) + ps2;
        float d3 = fminf(a.w, c.w) + ps3;
        float acc_pcl = d0 * am0 + d1 * am1 + d2 * am2 + d3 * am3;
        float acc_cub = cub0 * am0 + cub1 * am1 + cub2 * am2 + cub3 * am3;
        float acc_am  = am0 + am1 + am2 + am3;
        float s0 = wave_sum(acc_pcl);
        float s1 = wave_sum(acc_cub);
        float s2 = wave_sum(acc_am);
        const int lane_ = tid & 63, wave = tid >> 6;   // wave 0 or 1
        if (lane_ == 0) {
            wsum[wave * 3 + 0] = s0;
            wsum[wave * 3 + 1] = s1;
            wsum[wave * 3 + 2] = s2;
        }
    }

    // ---- Pass B: 4 s/thread, 8 point-replicas of 64 points each ----
    {
        const int rep = tid >> 5;     // 0..7
        const int sb  = tid & 31;
        const float4 x0 = Xs[sb];
        const float4 x1 = Xs[sb + 32];
        const float4 x2 = Xs[sb + 64];
        const float4 x3 = Xs[sb + 96];
        const int nb = rep * 64;
        float r0 = FINF, r1 = FINF, r2 = FINF, r3 = FINF;
        #pragma unroll 4
        for (int n = 0; n < 64; n += 2) {
            float4 pa = Pts[nb + n];
            float4 pb = Pts[nb + n + 1];
            float d;
            d = fmaf(x0.x, pa.x, fmaf(x0.y, pa.y, fmaf(x0.z, pa.z, pa.w))); r0 = fminf(r0, d);
            d = fmaf(x1.x, pa.x, fmaf(x1.y, pa.y, fmaf(x1.z, pa.z, pa.w))); r1 = fminf(r1, d);
            d = fmaf(x2.x, pa.x, fmaf(x2.y, pa.y, fmaf(x2.z, pa.z, pa.w))); r2 = fminf(r2, d);
            d = fmaf(x3.x, pa.x, fmaf(x3.y, pa.y, fmaf(x3.z, pa.z, pa.w))); r3 = fminf(r3, d);
            d = fmaf(x0.x, pb.x, fmaf(x0.y, pb.y, fmaf(x0.z, pb.z, pb.w))); r0 = fminf(r0, d);
            d = fmaf(x1.x, pb.x, fmaf(x1.y, pb.y, fmaf(x1.z, pb.z, pb.w))); r1 = fminf(r1, d);
            d = fmaf(x2.x, pb.x, fmaf(x2.y, pb.y, fmaf(x2.z, pb.z, pb.w))); r2 = fminf(r2, d);
            d = fmaf(x3.x, pb.x, fmaf(x3.y, pb.y, fmaf(x3.z, pb.z, pb.w))); r3 = fminf(r3, d);
        }
        red[rep * SS + sb +  0] = r0;   // d_eff2 = |p|^2 - 2x.p
        red[rep * SS + sb + 32] = r1;
        red[rep * SS + sb + 64] = r2;
        red[rep * SS + sb + 96] = r3;
    }
    __syncthreads();

    // ---- write partials: split-innermost 8-float groups -> coalesced finisher reads ----
    if (tid < SS) {
        float m = red[tid];
        #pragma unroll
        for (int r = 1; r < 8; ++r) m = fminf(m, red[r * SS + tid]);
        ws[(size_t)(bp * SS + tid) * 8 + split] = m + Xs[tid].w;  // + |x_s|^2
    }
    if (tid == 0) {
        float* sc = ws + SCAL_F + (bp * NSPLIT + split) * 4;
        sc[0] = wsum[0] + wsum[3];
        sc[1] = wsum[1] + wsum[4];
        sc[2] = wsum[2] + wsum[5];
    }

    // ---- last-block handoff (release: barrier drains vmem, fence publishes L2) ----
    __syncthreads();
    if (tid == 0) {
        __threadfence();
        s_flag = atomicAdd((unsigned int*)(ws + CNT_F), 1u);
    }
    __syncthreads();
    if (s_flag != (unsigned int)(GRID - 1)) return;
    __threadfence();   // acquire: invalidate stale caches before reading other blocks' partials

    // ================= final reduction (only the last block) =================
    // red[0..95]=prim sums, [96..191]=pcl, [192..287]=cub, [288..383]=bce,
    // [384..479]=e, [480..575]=sq
    if (tid < 96) red[tid] = 0.f;
    __syncthreads();

    const int lane = tid & 63;
    // per (bp,s): min over 6 splits; 12288 elems, 48 per thread.
    // wave covers 64 consecutive s of one bp -> same grouping as round-0 kernel 2.
    #pragma unroll 4
    for (int k = 0; k < 48; ++k) {
        const int idx = tid + (k << 8);
        const float4* m4 = ((const float4*)ws) + (idx << 1);
        const float4 a  = m4[0];
        const float4 b2 = m4[1];          // .z/.w are pad, never read
        float m = fminf(fminf(fminf(a.x, a.y), fminf(a.z, a.w)), fminf(b2.x, b2.y));
        float sm = wave_sum(m);           // bp uniform within wave
        if (lane == 0) atomicAdd(&red[idx >> 7], sm);
    }
    if (tid < 96) {
        const float* sc = ws + SCAL_F + tid * (NSPLIT * 4);
        float pcl = 0.f, cubv = 0.f, cs = 0.f;
        #pragma unroll
        for (int sp = 0; sp < NSPLIT; ++sp) {
            pcl  += sc[sp * 4 + 0];
            cubv += sc[sp * 4 + 1];
            cs   += sc[sp * 4 + 2];
        }
        const float e  = exist[tid];
        const float gt = (cs > 24.0f) ? 1.f : 0.f;
        red[ 96 + tid] = pcl;
        red[192 + tid] = cubv;
        red[288 + tid] = gt * logf(e) + (1.f - gt) * log1pf(-e);
        red[384 + tid] = e;
        red[480 + tid] = sqrtf(cs / (float)NN + 0.01f);
    }
    __syncthreads();

    if (tid == 0) {
        float pcl_sum = 0.f, cub_sum = 0.f, bce_sum = 0.f, prim_loss = 0.f, sps = 0.f;
        #pragma unroll
        for (int b_ = 0; b_ < BB; ++b_) {
            float pe = 0.f, ee = 0.f, sq = 0.f;
            #pragma unroll
            for (int p_ = 0; p_ < PP; ++p_) {
                const int i = b_ * PP + p_;
                pcl_sum += red[ 96 + i];
                cub_sum += red[192 + i];
                bce_sum += red[288 + i];
                pe += (red[i] / (float)SS) * red[384 + i];
                ee += red[384 + i];
                sq += red[480 + i];
            }
            prim_loss += pe / (ee + 1e-6f);
            float mb = sq / (float)PP;
            sps += mb * mb;
        }
        prim_loss /= (float)BB;
        sps       /= (float)BB;
        float pcl_loss = pcl_sum / (float)(BB * NN);
        float cubf     = cub_sum / (float)(BB * NN);
        float bce      = -bce_sum / (float)(BB * PP);
        out[0] = 0.1f * cubf + 1.0f * (pcl_loss + prim_loss) + 0.01f * bce + 0.01f * sps;
    }
}

extern "C" void kernel_launch(void* const* d_in, const int* in_sizes, int n_in,
                              void* d_out, int out_size, void* d_ws, size_t ws_size,
                              hipStream_t stream) {
    const float* pc     = (const float*)d_in[0];
    const float* nrm    = (const float*)d_in[1];
    const float* scale  = (const float*)d_in[2];
    const float* shape  = (const float*)d_in[3];
    const float* exist  = (const float*)d_in[4];
    const float* assign = (const float*)d_in[5];
    const float* etas   = (const float*)d_in[6];
    const float* omegas = (const float*)d_in[7];
    float* ws  = (float*)d_ws;
    float* out = (float*)d_out;

    // zero the completion counter (ws is poisoned by the harness each iteration);
    // plain kernel node -> graph-capture-safe
    superdec_zero<<<1, 1, 0, stream>>>(ws);

    superdec_fused<<<GRID, 256, 0, stream>>>(
        pc, nrm, scale, shape, exist, assign, etas, omegas, ws, out);
}

// Round 3
// 110.715 us; speedup vs baseline: 1.1147x; 1.1147x over previous
//
#include <hip/hip_runtime.h>
#include <math.h>

#define BB 4
#define PP 24
#define NN 3072
#define SS 128
#define CHUNK 512
#define NSPLIT 6             // NN / CHUNK
#define GRID (BB * PP * NSPLIT)   // 576
#define FINF 3.4e38f

// ws layout (32-bit slots):
//   [0, MINS_N)                 : uint monotonic-key per-(bp,s) running mins (init 0xFFFFFFFF)
//   [SCAL_F, SCAL_F + SCAL_N)   : float per-(bp,split) scalars {pcl, cub, asum, pad}
//   [CNT_F]                     : uint completion counter (init 0)
#define MINS_N (96 * SS)                 // 12288
#define SCAL_F MINS_N
#define SCAL_N (96 * NSPLIT * 4)
#define CNT_F  (SCAL_F + SCAL_N)

// ---- monotonic float<->uint order-preserving map (total order, any sign) ----
__device__ __forceinline__ unsigned key_of(float f) {
    unsigned u = __float_as_uint(f);
    return (u & 0x80000000u) ? ~u : (u | 0x80000000u);
}
__device__ __forceinline__ float val_of(unsigned k) {
    unsigned u = (k & 0x80000000u) ? (k ^ 0x80000000u) : ~k;
    return __uint_as_float(u);
}

__device__ __forceinline__ float fexp_f(float v, float p) {
    float m = powf(fabsf(v), p);
    float s = (v > 0.f) ? 1.f : ((v < 0.f) ? -1.f : 0.f);
    return s * m;
}
__device__ __forceinline__ float fix_f(float v) {
    return ((v > 0.f) ? 1.f : -1.f) * fmaxf(fabsf(v), 1e-6f);
}
__device__ __forceinline__ float wave_sum(float v) {
    #pragma unroll
    for (int off = 32; off > 0; off >>= 1) v += __shfl_down(v, off);
    return v;
}
__device__ __forceinline__ float cub_dist(float px, float py, float pz,
                                          float nx, float ny, float nz,
                                          float sc0, float sc1, float sc2) {
    // argmax over {-nx,nx,-ny,ny,-nz,nz}; strict > == jnp first-max rule
    float best = -nx; int idx = 0;
    if ( nx > best) { best =  nx; idx = 1; }
    if (-ny > best) { best = -ny; idx = 2; }
    if ( ny > best) { best =  ny; idx = 3; }
    if (-nz > best) { best = -nz; idx = 4; }
    if ( nz > best) { best =  nz; idx = 5; }
    const int c = idx >> 1;
    const float scc = (c == 0) ? sc0 : ((c == 1) ? sc1 : sc2);
    const float fv  = (idx & 1) ? scc : -scc;
    float pr0 = (c == 0) ? fv : fminf(fmaxf(px, -sc0), sc0);
    float pr1 = (c == 1) ? fv : fminf(fmaxf(py, -sc1), sc1);
    float pr2 = (c == 2) ? fv : fminf(fmaxf(pz, -sc2), sc2);
    float d0 = pr0 - px, d1 = pr1 - py, d2 = pr2 - pz;
    return fmaf(d0, d0, fmaf(d1, d1, d2 * d2));
}

// ---- init: seed min-keys to max, zero counter. Plain stores; end-of-kernel
// ---- implicit device-scope flush publishes them to the fused kernel.
__global__ __launch_bounds__(256) void superdec_init(float* __restrict__ ws) {
    const int i = blockIdx.x * 256 + threadIdx.x;   // grid = 48*256 = 12288
    ((unsigned*)ws)[i] = 0xFFFFFFFFu;
    if (i == 0) *(unsigned*)(ws + CNT_F) = 0u;
}

// ---- Fused kernel: 576 blocks x 256 threads; last-finishing block does the
// ---- final reduction. NO device fences: all cross-block traffic goes through
// ---- agent-scope atomics (performed at the coherent point, cross-XCD safe).
__global__ __launch_bounds__(256) void superdec_fused(
    const float* __restrict__ pc, const float* __restrict__ nrm,
    const float* __restrict__ scale, const float* __restrict__ shape,
    const float* __restrict__ exist, const float* __restrict__ assign,
    const float* __restrict__ etas, const float* __restrict__ omegas,
    float* __restrict__ ws, float* __restrict__ out)
{
    const int blk   = blockIdx.x;
    const int bp    = blk / NSPLIT;
    const int split = blk % NSPLIT;
    const int b     = bp / PP;
    const int p     = bp % PP;
    const int tid   = threadIdx.x;
    const int n0    = split * CHUNK;
    const int pid   = tid & 127;   // point-group id: points pid*4 .. pid*4+3
    const int q     = tid >> 7;    // s-half: 0 -> s[0,64), 1 -> s[64,128)

    __shared__ float4 Xs[SS];          // (-2x, -2y, -2z, |x|^2)
    __shared__ float4 Pts[CHUNK];      // ( x,   y,   z,  |p|^2)
    __shared__ float4 dmin2[2][128];   // per (half, pid): 4 per-point d_eff mins
    __shared__ float  red[8 * SS];     // pass-B replica mins; reused by finisher
    __shared__ float  wsum[6];
    __shared__ unsigned int s_flag;

    const float sc0 = scale[bp * 3 + 0];
    const float sc1 = scale[bp * 3 + 1];
    const float sc2 = scale[bp * 3 + 2];

    // ---- load this thread's 4 points via 3 contiguous float4 loads ----
    const float4* pc4 = (const float4*)(pc + ((size_t)bp * NN + n0) * 3);
    const float4 g0 = pc4[pid * 3 + 0];
    const float4 g1 = pc4[pid * 3 + 1];
    const float4 g2 = pc4[pid * 3 + 2];
    const float px0 = g0.x, py0 = g0.y, pz0 = g0.z;
    const float px1 = g0.w, py1 = g1.x, pz1 = g1.y;
    const float px2 = g1.z, py2 = g1.w, pz2 = g2.x;
    const float px3 = g2.y, py3 = g2.z, pz3 = g2.w;
    const float ps0 = fmaf(px0, px0, fmaf(py0, py0, pz0 * pz0));
    const float ps1 = fmaf(px1, px1, fmaf(py1, py1, pz1 * pz1));
    const float ps2 = fmaf(px2, px2, fmaf(py2, py2, pz2 * pz2));
    const float ps3 = fmaf(px3, px3, fmaf(py3, py3, pz3 * pz3));

    float cub0 = 0.f, cub1 = 0.f, cub2 = 0.f, cub3 = 0.f;
    float am0 = 0.f, am1 = 0.f, am2 = 0.f, am3 = 0.f;

    if (q == 0) {
        // superquadric samples (1 per thread)
        {
            const float e1 = shape[bp * 2 + 0];
            const float e2 = shape[bp * 2 + 1];
            float eta = etas[bp * SS + tid];
            float omg = omegas[bp * SS + tid];
            eta = (eta == 0.f) ? 1e-6f : eta;
            omg = (omg == 0.f) ? 1e-6f : omg;
            float ce = cosf(eta), se = sinf(eta);
            float co = cosf(omg), so = sinf(omg);
            float fce = fexp_f(ce, e1);
            float x = fix_f(sc0 * fce * fexp_f(co, e2));
            float y = fix_f(sc1 * fce * fexp_f(so, e2));
            float z = fix_f(sc2 * fexp_f(se, e1));
            float xsq = fmaf(x, x, fmaf(y, y, z * z));
            Xs[tid] = make_float4(-2.f * x, -2.f * y, -2.f * z, xsq);
        }
        // stage points for pass B
        Pts[pid * 4 + 0] = make_float4(px0, py0, pz0, ps0);
        Pts[pid * 4 + 1] = make_float4(px1, py1, pz1, ps1);
        Pts[pid * 4 + 2] = make_float4(px2, py2, pz2, ps2);
        Pts[pid * 4 + 3] = make_float4(px3, py3, pz3, ps3);
        // cuboid terms (normals used once; only half-0 loads them)
        const float4* nr4 = (const float4*)(nrm + ((size_t)bp * NN + n0) * 3);
        const float4 h0 = nr4[pid * 3 + 0];
        const float4 h1 = nr4[pid * 3 + 1];
        const float4 h2 = nr4[pid * 3 + 2];
        cub0 = cub_dist(px0, py0, pz0, h0.x, h0.y, h0.z, sc0, sc1, sc2);
        cub1 = cub_dist(px1, py1, pz1, h0.w, h1.x, h1.y, sc0, sc1, sc2);
        cub2 = cub_dist(px2, py2, pz2, h1.z, h1.w, h2.x, sc0, sc1, sc2);
        cub3 = cub_dist(px3, py3, pz3, h2.y, h2.z, h2.w, sc0, sc1, sc2);
        const size_t abase = ((size_t)b * NN + n0 + pid * 4) * PP + p;
        am0 = assign[abase + 0 * PP];
        am1 = assign[abase + 1 * PP];
        am2 = assign[abase + 2 * PP];
        am3 = assign[abase + 3 * PP];
    }
    __syncthreads();

    // ---- Pass A: min over this half's 64 s for 4 points (d_eff = |x|^2-2x.p) ----
    {
        const int sb = q * 64;
        float m0 = FINF, m1 = FINF, m2 = FINF, m3 = FINF;
        #pragma unroll 4
        for (int s = 0; s < 64; s += 2) {
            float4 xa = Xs[sb + s];
            float4 xb = Xs[sb + s + 1];
            float d;
            d = fmaf(xa.x, px0, fmaf(xa.y, py0, fmaf(xa.z, pz0, xa.w))); m0 = fminf(m0, d);
            d = fmaf(xa.x, px1, fmaf(xa.y, py1, fmaf(xa.z, pz1, xa.w))); m1 = fminf(m1, d);
            d = fmaf(xa.x, px2, fmaf(xa.y, py2, fmaf(xa.z, pz2, xa.w))); m2 = fminf(m2, d);
            d = fmaf(xa.x, px3, fmaf(xa.y, py3, fmaf(xa.z, pz3, xa.w))); m3 = fminf(m3, d);
            d = fmaf(xb.x, px0, fmaf(xb.y, py0, fmaf(xb.z, pz0, xb.w))); m0 = fminf(m0, d);
            d = fmaf(xb.x, px1, fmaf(xb.y, py1, fmaf(xb.z, pz1, xb.w))); m1 = fminf(m1, d);
            d = fmaf(xb.x, px2, fmaf(xb.y, py2, fmaf(xb.z, pz2, xb.w))); m2 = fminf(m2, d);
            d = fmaf(xb.x, px3, fmaf(xb.y, py3, fmaf(xb.z, pz3, xb.w))); m3 = fminf(m3, d);
        }
        dmin2[q][pid] = make_float4(m0, m1, m2, m3);
    }
    __syncthreads();

    // ---- half-0: combine s-halves, weight, wave-sum scalars ----
    if (q == 0) {
        float4 a = dmin2[0][pid];
        float4 c = dmin2[1][pid];
        float d0 = fminf(a.x, c.x) + ps0;
        float d1 = fminf(a.y, c.y) + ps1;
        float d2 = fminf(a.z, c.z) + ps2;
        float d3 = fminf(a.w, c.w) + ps3;
        float acc_pcl = d0 * am0 + d1 * am1 + d2 * am2 + d3 * am3;
        float acc_cub = cub0 * am0 + cub1 * am1 + cub2 * am2 + cub3 * am3;
        float acc_am  = am0 + am1 + am2 + am3;
        float s0 = wave_sum(acc_pcl);
        float s1 = wave_sum(acc_cub);
        float s2 = wave_sum(acc_am);
        const int lane_ = tid & 63, wave = tid >> 6;   // wave 0 or 1
        if (lane_ == 0) {
            wsum[wave * 3 + 0] = s0;
            wsum[wave * 3 + 1] = s1;
            wsum[wave * 3 + 2] = s2;
        }
    }

    // ---- Pass B: 4 s/thread, 8 point-replicas of 64 points each ----
    {
        const int rep = tid >> 5;     // 0..7
        const int sb  = tid & 31;
        const float4 x0 = Xs[sb];
        const float4 x1 = Xs[sb + 32];
        const float4 x2 = Xs[sb + 64];
        const float4 x3 = Xs[sb + 96];
        const int nb = rep * 64;
        float r0 = FINF, r1 = FINF, r2 = FINF, r3 = FINF;
        #pragma unroll 4
        for (int n = 0; n < 64; n += 2) {
            float4 pa = Pts[nb + n];
            float4 pb = Pts[nb + n + 1];
            float d;
            d = fmaf(x0.x, pa.x, fmaf(x0.y, pa.y, fmaf(x0.z, pa.z, pa.w))); r0 = fminf(r0, d);
            d = fmaf(x1.x, pa.x, fmaf(x1.y, pa.y, fmaf(x1.z, pa.z, pa.w))); r1 = fminf(r1, d);
            d = fmaf(x2.x, pa.x, fmaf(x2.y, pa.y, fmaf(x2.z, pa.z, pa.w))); r2 = fminf(r2, d);
            d = fmaf(x3.x, pa.x, fmaf(x3.y, pa.y, fmaf(x3.z, pa.z, pa.w))); r3 = fminf(r3, d);
            d = fmaf(x0.x, pb.x, fmaf(x0.y, pb.y, fmaf(x0.z, pb.z, pb.w))); r0 = fminf(r0, d);
            d = fmaf(x1.x, pb.x, fmaf(x1.y, pb.y, fmaf(x1.z, pb.z, pb.w))); r1 = fminf(r1, d);
            d = fmaf(x2.x, pb.x, fmaf(x2.y, pb.y, fmaf(x2.z, pb.z, pb.w))); r2 = fminf(r2, d);
            d = fmaf(x3.x, pb.x, fmaf(x3.y, pb.y, fmaf(x3.z, pb.z, pb.w))); r3 = fminf(r3, d);
        }
        red[rep * SS + sb +  0] = r0;   // d_eff2 = |p|^2 - 2x.p
        red[rep * SS + sb + 32] = r1;
        red[rep * SS + sb + 64] = r2;
        red[rep * SS + sb + 96] = r3;
    }
    __syncthreads();

    // ---- publish partials via agent-scope atomics (write-through; no fences) ----
    if (tid < SS) {
        float m = red[tid];
        #pragma unroll
        for (int r = 1; r < 8; ++r) m = fminf(m, red[r * SS + tid]);
        const float v = m + Xs[tid].w;          // + |x_s|^2 -> true min distance
        __hip_atomic_fetch_min((unsigned*)ws + (bp * SS + tid), key_of(v),
                               __ATOMIC_RELAXED, __HIP_MEMORY_SCOPE_AGENT);
    }
    if (tid == 0) {
        float* sc = ws + SCAL_F + (bp * NSPLIT + split) * 4;
        __hip_atomic_store(sc + 0, wsum[0] + wsum[3], __ATOMIC_RELAXED, __HIP_MEMORY_SCOPE_AGENT);
        __hip_atomic_store(sc + 1, wsum[1] + wsum[4], __ATOMIC_RELAXED, __HIP_MEMORY_SCOPE_AGENT);
        __hip_atomic_store(sc + 2, wsum[2] + wsum[5], __ATOMIC_RELAXED, __HIP_MEMORY_SCOPE_AGENT);
    }

    // ---- last-block handoff: __syncthreads drains every wave's vmcnt (atomics
    // ---- ack'd at coherent point) before tid0 bumps the counter. No fence.
    __syncthreads();
    if (tid == 0) {
        asm volatile("s_waitcnt vmcnt(0)" ::: "memory");   // belt-and-braces for wave 0
        s_flag = __hip_atomic_fetch_add((unsigned*)(ws + CNT_F), 1u,
                                        __ATOMIC_RELAXED, __HIP_MEMORY_SCOPE_AGENT);
    }
    __syncthreads();
    if (s_flag != (unsigned)(GRID - 1)) return;

    // ================= final reduction (only the last block) =================
    // All cross-block reads use agent-scope atomic loads (bypass stale L1/L2).
    // red[0..95]=prim sums, [96..191]=pcl, [192..287]=cub, [288..383]=bce,
    // [384..479]=e, [480..575]=sq
    if (tid < 96) red[tid] = 0.f;
    __syncthreads();

    const int lane = tid & 63;
    const unsigned* minu = (const unsigned*)ws;
    // per (bp,s): 12288 combined mins, 48 per thread; each wave covers 64
    // consecutive s of one bp -> identical wave_sum grouping as round 0.
    for (int k = 0; k < 48; ++k) {
        const int idx = tid + (k << 8);
        float m = val_of(__hip_atomic_load(minu + idx, __ATOMIC_RELAXED,
                                           __HIP_MEMORY_SCOPE_AGENT));
        float sm = wave_sum(m);           // bp uniform within wave
        if (lane == 0) atomicAdd(&red[idx >> 7], sm);
    }
    if (tid < 96) {
        const float* sc = ws + SCAL_F + tid * (NSPLIT * 4);
        float pcl = 0.f, cubv = 0.f, cs = 0.f;
        #pragma unroll
        for (int sp = 0; sp < NSPLIT; ++sp) {
            pcl  += __hip_atomic_load(sc + sp * 4 + 0, __ATOMIC_RELAXED, __HIP_MEMORY_SCOPE_AGENT);
            cubv += __hip_atomic_load(sc + sp * 4 + 1, __ATOMIC_RELAXED, __HIP_MEMORY_SCOPE_AGENT);
            cs   += __hip_atomic_load(sc + sp * 4 + 2, __ATOMIC_RELAXED, __HIP_MEMORY_SCOPE_AGENT);
        }
        const float e  = exist[tid];
        const float gt = (cs > 24.0f) ? 1.f : 0.f;
        red[ 96 + tid] = pcl;
        red[192 + tid] = cubv;
        red[288 + tid] = gt * logf(e) + (1.f - gt) * log1pf(-e);
        red[384 + tid] = e;
        red[480 + tid] = sqrtf(cs / (float)NN + 0.01f);
    }
    __syncthreads();

    if (tid == 0) {
        float pcl_sum = 0.f, cub_sum = 0.f, bce_sum = 0.f, prim_loss = 0.f, sps = 0.f;
        #pragma unroll
        for (int b_ = 0; b_ < BB; ++b_) {
            float pe = 0.f, ee = 0.f, sq = 0.f;
            #pragma unroll
            for (int p_ = 0; p_ < PP; ++p_) {
                const int i = b_ * PP + p_;
                pcl_sum += red[ 96 + i];
                cub_sum += red[192 + i];
                bce_sum += red[288 + i];
                pe += (red[i] / (float)SS) * red[384 + i];
                ee += red[384 + i];
                sq += red[480 + i];
            }
            prim_loss += pe / (ee + 1e-6f);
            float mb = sq / (float)PP;
            sps += mb * mb;
        }
        prim_loss /= (float)BB;
        sps       /= (float)BB;
        float pcl_loss = pcl_sum / (float)(BB * NN);
        float cubf     = cub_sum / (float)(BB * NN);
        float bce      = -bce_sum / (float)(BB * PP);
        out[0] = 0.1f * cubf + 1.0f * (pcl_loss + prim_loss) + 0.01f * bce + 0.01f * sps;
    }
}

extern "C" void kernel_launch(void* const* d_in, const int* in_sizes, int n_in,
                              void* d_out, int out_size, void* d_ws, size_t ws_size,
                              hipStream_t stream) {
    const float* pc     = (const float*)d_in[0];
    const float* nrm    = (const float*)d_in[1];
    const float* scale  = (const float*)d_in[2];
    const float* shape  = (const float*)d_in[3];
    const float* exist  = (const float*)d_in[4];
    const float* assign = (const float*)d_in[5];
    const float* etas   = (const float*)d_in[6];
    const float* omegas = (const float*)d_in[7];
    float* ws  = (float*)d_ws;
    float* out = (float*)d_out;

    // seed min-keys + counter (plain kernel node; implicit end-of-kernel flush
    // publishes before superdec_fused starts)
    superdec_init<<<MINS_N / 256, 256, 0, stream>>>(ws);

    superdec_fused<<<GRID, 256, 0, stream>>>(
        pc, nrm, scale, shape, exist, assign, etas, omegas, ws, out);
}

// Round 4
// 102.095 us; speedup vs baseline: 1.2088x; 1.0844x over previous
//
#include <hip/hip_runtime.h>
#include <math.h>

#define BB 4
#define PP 24
#define NN 3072
#define SS 128
#define CHUNK 512
#define NSPLIT 6             // NN / CHUNK
#define GRID (BB * PP * NSPLIT)   // 576
#define FINF 3.4e38f

// ws layout (32-bit slots):
//   [0, MINS_N)                 : uint monotonic-key per-(bp,s) running mins (init 0xFFFFFFFF)
//   [SCAL_F, SCAL_F + SCAL_N)   : float per-(bp,split) scalars {pcl, cub, asum, pad}
//   [CNT_F]                     : uint completion counter (init 0)
#define MINS_N (96 * SS)                 // 12288
#define SCAL_F MINS_N
#define SCAL_N (96 * NSPLIT * 4)
#define CNT_F  (SCAL_F + SCAL_N)

// ---- monotonic float<->uint order-preserving map (total order, any sign) ----
__device__ __forceinline__ unsigned key_of(float f) {
    unsigned u = __float_as_uint(f);
    return (u & 0x80000000u) ? ~u : (u | 0x80000000u);
}
__device__ __forceinline__ float val_of(unsigned k) {
    unsigned u = (k & 0x80000000u) ? (k ^ 0x80000000u) : ~k;
    return __uint_as_float(u);
}

__device__ __forceinline__ float fexp_f(float v, float p) {
    float m = powf(fabsf(v), p);
    float s = (v > 0.f) ? 1.f : ((v < 0.f) ? -1.f : 0.f);
    return s * m;
}
__device__ __forceinline__ float fix_f(float v) {
    return ((v > 0.f) ? 1.f : -1.f) * fmaxf(fabsf(v), 1e-6f);
}
__device__ __forceinline__ float wave_sum(float v) {
    #pragma unroll
    for (int off = 32; off > 0; off >>= 1) v += __shfl_down(v, off);
    return v;
}
__device__ __forceinline__ float cub_dist(float px, float py, float pz,
                                          float nx, float ny, float nz,
                                          float sc0, float sc1, float sc2) {
    // argmax over {-nx,nx,-ny,ny,-nz,nz}; strict > == jnp first-max rule
    float best = -nx; int idx = 0;
    if ( nx > best) { best =  nx; idx = 1; }
    if (-ny > best) { best = -ny; idx = 2; }
    if ( ny > best) { best =  ny; idx = 3; }
    if (-nz > best) { best = -nz; idx = 4; }
    if ( nz > best) { best =  nz; idx = 5; }
    const int c = idx >> 1;
    const float scc = (c == 0) ? sc0 : ((c == 1) ? sc1 : sc2);
    const float fv  = (idx & 1) ? scc : -scc;
    float pr0 = (c == 0) ? fv : fminf(fmaxf(px, -sc0), sc0);
    float pr1 = (c == 1) ? fv : fminf(fmaxf(py, -sc1), sc1);
    float pr2 = (c == 2) ? fv : fminf(fmaxf(pz, -sc2), sc2);
    float d0 = pr0 - px, d1 = pr1 - py, d2 = pr2 - pz;
    return fmaf(d0, d0, fmaf(d1, d1, d2 * d2));
}

// ---- init: seed min-keys to max, zero counter. Plain stores; end-of-kernel
// ---- implicit device-scope flush publishes them to the fused kernel.
__global__ __launch_bounds__(256) void superdec_init(float* __restrict__ ws) {
    const int i = blockIdx.x * 256 + threadIdx.x;   // grid = 48*256 = 12288
    ((unsigned*)ws)[i] = 0xFFFFFFFFu;
    if (i == 0) *(unsigned*)(ws + CNT_F) = 0u;
}

// ---- Fused kernel: 576 blocks x 256 threads; last-finishing block does the
// ---- final reduction. NO device fences: all cross-block traffic goes through
// ---- agent-scope atomics (performed at the coherent point, cross-XCD safe).
__global__ __launch_bounds__(256) void superdec_fused(
    const float* __restrict__ pc, const float* __restrict__ nrm,
    const float* __restrict__ scale, const float* __restrict__ shape,
    const float* __restrict__ exist, const float* __restrict__ assign,
    const float* __restrict__ etas, const float* __restrict__ omegas,
    float* __restrict__ ws, float* __restrict__ out)
{
    const int blk   = blockIdx.x;
    const int bp    = blk / NSPLIT;
    const int split = blk % NSPLIT;
    const int b     = bp / PP;
    const int p     = bp % PP;
    const int tid   = threadIdx.x;
    const int n0    = split * CHUNK;
    const int pid   = tid & 127;   // point-group id: points pid*4 .. pid*4+3
    const int q     = tid >> 7;    // s-half: 0 -> s[0,64), 1 -> s[64,128)

    __shared__ float4 Xs[SS];          // (-2x, -2y, -2z, |x|^2)
    __shared__ float4 Pts[CHUNK];      // ( x,   y,   z,  |p|^2)
    __shared__ float4 dmin2[2][128];   // per (half, pid): 4 per-point d_eff mins
    __shared__ float  red[8 * SS];     // pass-B replica mins; reused by finisher
    __shared__ float  wsum[6];
    __shared__ unsigned int s_flag;

    const float sc0 = scale[bp * 3 + 0];
    const float sc1 = scale[bp * 3 + 1];
    const float sc2 = scale[bp * 3 + 2];

    // ---- load this thread's 4 points via 3 contiguous float4 loads ----
    const float4* pc4 = (const float4*)(pc + ((size_t)bp * NN + n0) * 3);
    const float4 g0 = pc4[pid * 3 + 0];
    const float4 g1 = pc4[pid * 3 + 1];
    const float4 g2 = pc4[pid * 3 + 2];
    const float px0 = g0.x, py0 = g0.y, pz0 = g0.z;
    const float px1 = g0.w, py1 = g1.x, pz1 = g1.y;
    const float px2 = g1.z, py2 = g1.w, pz2 = g2.x;
    const float px3 = g2.y, py3 = g2.z, pz3 = g2.w;
    const float ps0 = fmaf(px0, px0, fmaf(py0, py0, pz0 * pz0));
    const float ps1 = fmaf(px1, px1, fmaf(py1, py1, pz1 * pz1));
    const float ps2 = fmaf(px2, px2, fmaf(py2, py2, pz2 * pz2));
    const float ps3 = fmaf(px3, px3, fmaf(py3, py3, pz3 * pz3));

    float cub0 = 0.f, cub1 = 0.f, cub2 = 0.f, cub3 = 0.f;
    float am0 = 0.f, am1 = 0.f, am2 = 0.f, am3 = 0.f;

    if (q == 0) {
        // superquadric samples (1 per thread)
        {
            const float e1 = shape[bp * 2 + 0];
            const float e2 = shape[bp * 2 + 1];
            float eta = etas[bp * SS + tid];
            float omg = omegas[bp * SS + tid];
            eta = (eta == 0.f) ? 1e-6f : eta;
            omg = (omg == 0.f) ? 1e-6f : omg;
            float ce = cosf(eta), se = sinf(eta);
            float co = cosf(omg), so = sinf(omg);
            float fce = fexp_f(ce, e1);
            float x = fix_f(sc0 * fce * fexp_f(co, e2));
            float y = fix_f(sc1 * fce * fexp_f(so, e2));
            float z = fix_f(sc2 * fexp_f(se, e1));
            float xsq = fmaf(x, x, fmaf(y, y, z * z));
            Xs[tid] = make_float4(-2.f * x, -2.f * y, -2.f * z, xsq);
        }
        // stage points for pass B
        Pts[pid * 4 + 0] = make_float4(px0, py0, pz0, ps0);
        Pts[pid * 4 + 1] = make_float4(px1, py1, pz1, ps1);
        Pts[pid * 4 + 2] = make_float4(px2, py2, pz2, ps2);
        Pts[pid * 4 + 3] = make_float4(px3, py3, pz3, ps3);
        // cuboid terms (normals used once; only half-0 loads them)
        const float4* nr4 = (const float4*)(nrm + ((size_t)bp * NN + n0) * 3);
        const float4 h0 = nr4[pid * 3 + 0];
        const float4 h1 = nr4[pid * 3 + 1];
        const float4 h2 = nr4[pid * 3 + 2];
        cub0 = cub_dist(px0, py0, pz0, h0.x, h0.y, h0.z, sc0, sc1, sc2);
        cub1 = cub_dist(px1, py1, pz1, h0.w, h1.x, h1.y, sc0, sc1, sc2);
        cub2 = cub_dist(px2, py2, pz2, h1.z, h1.w, h2.x, sc0, sc1, sc2);
        cub3 = cub_dist(px3, py3, pz3, h2.y, h2.z, h2.w, sc0, sc1, sc2);
        const size_t abase = ((size_t)b * NN + n0 + pid * 4) * PP + p;
        am0 = assign[abase + 0 * PP];
        am1 = assign[abase + 1 * PP];
        am2 = assign[abase + 2 * PP];
        am3 = assign[abase + 3 * PP];
    }
    __syncthreads();

    // ---- Pass A: min over this half's 64 s for 4 points (d_eff = |x|^2-2x.p) ----
    {
        const int sb = q * 64;
        float m0 = FINF, m1 = FINF, m2 = FINF, m3 = FINF;
        #pragma unroll 4
        for (int s = 0; s < 64; s += 2) {
            float4 xa = Xs[sb + s];
            float4 xb = Xs[sb + s + 1];
            float d;
            d = fmaf(xa.x, px0, fmaf(xa.y, py0, fmaf(xa.z, pz0, xa.w))); m0 = fminf(m0, d);
            d = fmaf(xa.x, px1, fmaf(xa.y, py1, fmaf(xa.z, pz1, xa.w))); m1 = fminf(m1, d);
            d = fmaf(xa.x, px2, fmaf(xa.y, py2, fmaf(xa.z, pz2, xa.w))); m2 = fminf(m2, d);
            d = fmaf(xa.x, px3, fmaf(xa.y, py3, fmaf(xa.z, pz3, xa.w))); m3 = fminf(m3, d);
            d = fmaf(xb.x, px0, fmaf(xb.y, py0, fmaf(xb.z, pz0, xb.w))); m0 = fminf(m0, d);
            d = fmaf(xb.x, px1, fmaf(xb.y, py1, fmaf(xb.z, pz1, xb.w))); m1 = fminf(m1, d);
            d = fmaf(xb.x, px2, fmaf(xb.y, py2, fmaf(xb.z, pz2, xb.w))); m2 = fminf(m2, d);
            d = fmaf(xb.x, px3, fmaf(xb.y, py3, fmaf(xb.z, pz3, xb.w))); m3 = fminf(m3, d);
        }
        dmin2[q][pid] = make_float4(m0, m1, m2, m3);
    }
    __syncthreads();

    // ---- half-0: combine s-halves, weight, wave-sum scalars ----
    if (q == 0) {
        float4 a = dmin2[0][pid];
        float4 c = dmin2[1][pid];
        float d0 = fminf(a.x, c.x) + ps0;
        float d1 = fminf(a.y, c.y) + ps1;
        float d2 = fminf(a.z, c.z) + ps2;
        float d3 = fminf(a.w, c.w) + ps3;
        float acc_pcl = d0 * am0 + d1 * am1 + d2 * am2 + d3 * am3;
        float acc_cub = cub0 * am0 + cub1 * am1 + cub2 * am2 + cub3 * am3;
        float acc_am  = am0 + am1 + am2 + am3;
        float s0 = wave_sum(acc_pcl);
        float s1 = wave_sum(acc_cub);
        float s2 = wave_sum(acc_am);
        const int lane_ = tid & 63, wave = tid >> 6;   // wave 0 or 1
        if (lane_ == 0) {
            wsum[wave * 3 + 0] = s0;
            wsum[wave * 3 + 1] = s1;
            wsum[wave * 3 + 2] = s2;
        }
    }

    // ---- Pass B: 4 s/thread, 8 point-replicas of 64 points each ----
    {
        const int rep = tid >> 5;     // 0..7
        const int sb  = tid & 31;
        const float4 x0 = Xs[sb];
        const float4 x1 = Xs[sb + 32];
        const float4 x2 = Xs[sb + 64];
        const float4 x3 = Xs[sb + 96];
        const int nb = rep * 64;
        float r0 = FINF, r1 = FINF, r2 = FINF, r3 = FINF;
        #pragma unroll 4
        for (int n = 0; n < 64; n += 2) {
            float4 pa = Pts[nb + n];
            float4 pb = Pts[nb + n + 1];
            float d;
            d = fmaf(x0.x, pa.x, fmaf(x0.y, pa.y, fmaf(x0.z, pa.z, pa.w))); r0 = fminf(r0, d);
            d = fmaf(x1.x, pa.x, fmaf(x1.y, pa.y, fmaf(x1.z, pa.z, pa.w))); r1 = fminf(r1, d);
            d = fmaf(x2.x, pa.x, fmaf(x2.y, pa.y, fmaf(x2.z, pa.z, pa.w))); r2 = fminf(r2, d);
            d = fmaf(x3.x, pa.x, fmaf(x3.y, pa.y, fmaf(x3.z, pa.z, pa.w))); r3 = fminf(r3, d);
            d = fmaf(x0.x, pb.x, fmaf(x0.y, pb.y, fmaf(x0.z, pb.z, pb.w))); r0 = fminf(r0, d);
            d = fmaf(x1.x, pb.x, fmaf(x1.y, pb.y, fmaf(x1.z, pb.z, pb.w))); r1 = fminf(r1, d);
            d = fmaf(x2.x, pb.x, fmaf(x2.y, pb.y, fmaf(x2.z, pb.z, pb.w))); r2 = fminf(r2, d);
            d = fmaf(x3.x, pb.x, fmaf(x3.y, pb.y, fmaf(x3.z, pb.z, pb.w))); r3 = fminf(r3, d);
        }
        red[rep * SS + sb +  0] = r0;   // d_eff2 = |p|^2 - 2x.p
        red[rep * SS + sb + 32] = r1;
        red[rep * SS + sb + 64] = r2;
        red[rep * SS + sb + 96] = r3;
    }
    __syncthreads();

    // ---- publish partials via agent-scope atomics (write-through; no fences) ----
    if (tid < SS) {
        float m = red[tid];
        #pragma unroll
        for (int r = 1; r < 8; ++r) m = fminf(m, red[r * SS + tid]);
        const float v = m + Xs[tid].w;          // + |x_s|^2 -> true min distance
        __hip_atomic_fetch_min((unsigned*)ws + (bp * SS + tid), key_of(v),
                               __ATOMIC_RELAXED, __HIP_MEMORY_SCOPE_AGENT);
    }
    if (tid == 0) {
        float* sc = ws + SCAL_F + (bp * NSPLIT + split) * 4;
        __hip_atomic_store(sc + 0, wsum[0] + wsum[3], __ATOMIC_RELAXED, __HIP_MEMORY_SCOPE_AGENT);
        __hip_atomic_store(sc + 1, wsum[1] + wsum[4], __ATOMIC_RELAXED, __HIP_MEMORY_SCOPE_AGENT);
        __hip_atomic_store(sc + 2, wsum[2] + wsum[5], __ATOMIC_RELAXED, __HIP_MEMORY_SCOPE_AGENT);
    }

    // ---- last-block handoff: __syncthreads drains every wave's vmcnt (atomics
    // ---- ack'd at coherent point) before tid0 bumps the counter. No fence.
    __syncthreads();
    if (tid == 0) {
        asm volatile("s_waitcnt vmcnt(0)" ::: "memory");   // belt-and-braces for wave 0
        s_flag = __hip_atomic_fetch_add((unsigned*)(ws + CNT_F), 1u,
                                        __ATOMIC_RELAXED, __HIP_MEMORY_SCOPE_AGENT);
    }
    __syncthreads();
    if (s_flag != (unsigned)(GRID - 1)) return;

    // ================= final reduction (only the last block) =================
    // All cross-block reads use agent-scope atomic loads (bypass stale L1/L2),
    // software-pipelined 8-deep so the coherent-point latency overlaps.
    // red[0..95]=prim sums, [96..191]=pcl, [192..287]=cub, [288..383]=bce,
    // [384..479]=e, [480..575]=sq
    if (tid < 96) red[tid] = 0.f;
    __syncthreads();

    const int lane = tid & 63;
    const unsigned* minu = (const unsigned*)ws;
    // per (bp,s): 12288 combined mins, 48 per thread; each wave covers 64
    // consecutive s of one bp -> identical wave_sum grouping as round 0.
    for (int k0 = 0; k0 < 48; k0 += 8) {
        float v[8];
        #pragma unroll
        for (int j = 0; j < 8; ++j) {
            v[j] = val_of(__hip_atomic_load(minu + tid + ((k0 + j) << 8),
                                            __ATOMIC_RELAXED, __HIP_MEMORY_SCOPE_AGENT));
        }
        #pragma unroll
        for (int j = 0; j < 8; ++j) {
            float sm = wave_sum(v[j]);        // bp uniform within wave
            if (lane == 0) atomicAdd(&red[(tid + ((k0 + j) << 8)) >> 7], sm);
        }
    }
    if (tid < 96) {
        const float* sc = ws + SCAL_F + tid * (NSPLIT * 4);
        float tp[NSPLIT], tc[NSPLIT], ta[NSPLIT];
        #pragma unroll
        for (int sp = 0; sp < NSPLIT; ++sp) {     // all 18 loads issued up front
            tp[sp] = __hip_atomic_load(sc + sp * 4 + 0, __ATOMIC_RELAXED, __HIP_MEMORY_SCOPE_AGENT);
            tc[sp] = __hip_atomic_load(sc + sp * 4 + 1, __ATOMIC_RELAXED, __HIP_MEMORY_SCOPE_AGENT);
            ta[sp] = __hip_atomic_load(sc + sp * 4 + 2, __ATOMIC_RELAXED, __HIP_MEMORY_SCOPE_AGENT);
        }
        float pcl = 0.f, cubv = 0.f, cs = 0.f;
        #pragma unroll
        for (int sp = 0; sp < NSPLIT; ++sp) {     // same summation order as before
            pcl += tp[sp]; cubv += tc[sp]; cs += ta[sp];
        }
        const float e  = exist[tid];
        const float gt = (cs > 24.0f) ? 1.f : 0.f;
        red[ 96 + tid] = pcl;
        red[192 + tid] = cubv;
        red[288 + tid] = gt * logf(e) + (1.f - gt) * log1pf(-e);
        red[384 + tid] = e;
        red[480 + tid] = sqrtf(cs / (float)NN + 0.01f);
    }
    __syncthreads();

    if (tid == 0) {
        float pcl_sum = 0.f, cub_sum = 0.f, bce_sum = 0.f, prim_loss = 0.f, sps = 0.f;
        #pragma unroll
        for (int b_ = 0; b_ < BB; ++b_) {
            float pe = 0.f, ee = 0.f, sq = 0.f;
            #pragma unroll
            for (int p_ = 0; p_ < PP; ++p_) {
                const int i = b_ * PP + p_;
                pcl_sum += red[ 96 + i];
                cub_sum += red[192 + i];
                bce_sum += red[288 + i];
                pe += (red[i] / (float)SS) * red[384 + i];
                ee += red[384 + i];
                sq += red[480 + i];
            }
            prim_loss += pe / (ee + 1e-6f);
            float mb = sq / (float)PP;
            sps += mb * mb;
        }
        prim_loss /= (float)BB;
        sps       /= (float)BB;
        float pcl_loss = pcl_sum / (float)(BB * NN);
        float cubf     = cub_sum / (float)(BB * NN);
        float bce      = -bce_sum / (float)(BB * PP);
        out[0] = 0.1f * cubf + 1.0f * (pcl_loss + prim_loss) + 0.01f * bce + 0.01f * sps;
    }
}

extern "C" void kernel_launch(void* const* d_in, const int* in_sizes, int n_in,
                              void* d_out, int out_size, void* d_ws, size_t ws_size,
                              hipStream_t stream) {
    const float* pc     = (const float*)d_in[0];
    const float* nrm    = (const float*)d_in[1];
    const float* scale  = (const float*)d_in[2];
    const float* shape  = (const float*)d_in[3];
    const float* exist  = (const float*)d_in[4];
    const float* assign = (const float*)d_in[5];
    const float* etas   = (const float*)d_in[6];
    const float* omegas = (const float*)d_in[7];
    float* ws  = (float*)d_ws;
    float* out = (float*)d_out;

    // seed min-keys + counter (plain kernel node; implicit end-of-kernel flush
    // publishes before superdec_fused starts)
    superdec_init<<<MINS_N / 256, 256, 0, stream>>>(ws);

    superdec_fused<<<GRID, 256, 0, stream>>>(
        pc, nrm, scale, shape, exist, assign, etas, omegas, ws, out);
}

// Round 5
// 89.226 us; speedup vs baseline: 1.3831x; 1.1442x over previous
//
#include <hip/hip_runtime.h>
#include <math.h>

#define BB 4
#define PP 24
#define NN 3072
#define SS 128
#define CHUNK 512
#define NSPLIT 6             // NN / CHUNK
#define GRID (BB * PP * NSPLIT)   // 576
#define FINF 3.4e38f

// ws layout (floats):
//   [SMIN_F, +96*128*8)   : per-(bp,s) split mins, slot (bp*128+s)*8 + split (2 pad)
//   [SCAL_F, +96*6*4)     : per-(bp,split) scalars {pcl, cub, asum, pad}
//   [BPRES_F, +96*4)      : per-bp results {prim, pcl, cub, asum}
//   [CNT_F, +97)          : 96 per-bp counters + 1 global counter (zeroed each launch)
#define SMIN_F  0
#define SCAL_F  (96 * SS * 8)            // 98304
#define BPRES_F (SCAL_F + 96 * NSPLIT * 4)
#define CNT_F   (BPRES_F + 96 * 4)

__device__ __forceinline__ float fexp_f(float v, float p) {
    float m = powf(fabsf(v), p);
    float s = (v > 0.f) ? 1.f : ((v < 0.f) ? -1.f : 0.f);
    return s * m;
}
__device__ __forceinline__ float fix_f(float v) {
    return ((v > 0.f) ? 1.f : -1.f) * fmaxf(fabsf(v), 1e-6f);
}
__device__ __forceinline__ float wave_sum(float v) {
    #pragma unroll
    for (int off = 32; off > 0; off >>= 1) v += __shfl_down(v, off);
    return v;
}
__device__ __forceinline__ float aload(const float* p) {
    return __hip_atomic_load(p, __ATOMIC_RELAXED, __HIP_MEMORY_SCOPE_AGENT);
}
__device__ __forceinline__ void astore(float* p, float v) {
    __hip_atomic_store(p, v, __ATOMIC_RELAXED, __HIP_MEMORY_SCOPE_AGENT);
}
__device__ __forceinline__ float cub_dist(float px, float py, float pz,
                                          float nx, float ny, float nz,
                                          float sc0, float sc1, float sc2) {
    // argmax over {-nx,nx,-ny,ny,-nz,nz}; strict > == jnp first-max rule
    float best = -nx; int idx = 0;
    if ( nx > best) { best =  nx; idx = 1; }
    if (-ny > best) { best = -ny; idx = 2; }
    if ( ny > best) { best =  ny; idx = 3; }
    if (-nz > best) { best = -nz; idx = 4; }
    if ( nz > best) { best =  nz; idx = 5; }
    const int c = idx >> 1;
    const float scc = (c == 0) ? sc0 : ((c == 1) ? sc1 : sc2);
    const float fv  = (idx & 1) ? scc : -scc;
    float pr0 = (c == 0) ? fv : fminf(fmaxf(px, -sc0), sc0);
    float pr1 = (c == 1) ? fv : fminf(fmaxf(py, -sc1), sc1);
    float pr2 = (c == 2) ? fv : fminf(fmaxf(pz, -sc2), sc2);
    float d0 = pr0 - px, d1 = pr1 - py, d2 = pr2 - pz;
    return fmaf(d0, d0, fmaf(d1, d1, d2 * d2));
}

// ---- init: zero the 97 counters only (1 block; everything else is
// ---- overwritten by value-carrying atomic stores each launch).
__global__ __launch_bounds__(128) void superdec_init(float* __restrict__ ws) {
    const int i = threadIdx.x;
    if (i < 97) ((unsigned*)(ws + CNT_F))[i] = 0u;
}

// ---- Fused kernel: 576 blocks x 256 threads.
// ---- Hierarchical finish: 6th split-block of each bp reduces that bp (~2us,
// ---- overlapped across 96 CUs); 96th bp-finisher does the tiny global final.
// ---- All cross-block traffic via agent-scope atomics (coherent point,
// ---- cross-XCD safe) -- no fences anywhere.
__global__ __launch_bounds__(256) void superdec_fused(
    const float* __restrict__ pc, const float* __restrict__ nrm,
    const float* __restrict__ scale, const float* __restrict__ shape,
    const float* __restrict__ exist, const float* __restrict__ assign,
    const float* __restrict__ etas, const float* __restrict__ omegas,
    float* __restrict__ ws, float* __restrict__ out)
{
    const int blk   = blockIdx.x;
    const int bp    = blk / NSPLIT;
    const int split = blk % NSPLIT;
    const int b     = bp / PP;
    const int p     = bp % PP;
    const int tid   = threadIdx.x;
    const int n0    = split * CHUNK;
    const int pid   = tid & 127;   // point-group id: points pid*4 .. pid*4+3
    const int q     = tid >> 7;    // s-half: 0 -> s[0,64), 1 -> s[64,128)

    __shared__ float4 Xs[SS];          // (-2x, -2y, -2z, |x|^2)
    __shared__ float4 Pts[CHUNK];      // ( x,   y,   z,  |p|^2)
    __shared__ float4 dmin2[2][128];   // per (half, pid): 4 per-point d_eff mins
    __shared__ float  red[8 * SS];     // pass-B replica mins; reused by finishers
    __shared__ float  wsum[6];
    __shared__ unsigned int s_cnt1, s_cnt2;

    const float sc0 = scale[bp * 3 + 0];
    const float sc1 = scale[bp * 3 + 1];
    const float sc2 = scale[bp * 3 + 2];

    // ---- load this thread's 4 points via 3 contiguous float4 loads ----
    const float4* pc4 = (const float4*)(pc + ((size_t)bp * NN + n0) * 3);
    const float4 g0 = pc4[pid * 3 + 0];
    const float4 g1 = pc4[pid * 3 + 1];
    const float4 g2 = pc4[pid * 3 + 2];
    const float px0 = g0.x, py0 = g0.y, pz0 = g0.z;
    const float px1 = g0.w, py1 = g1.x, pz1 = g1.y;
    const float px2 = g1.z, py2 = g1.w, pz2 = g2.x;
    const float px3 = g2.y, py3 = g2.z, pz3 = g2.w;
    const float ps0 = fmaf(px0, px0, fmaf(py0, py0, pz0 * pz0));
    const float ps1 = fmaf(px1, px1, fmaf(py1, py1, pz1 * pz1));
    const float ps2 = fmaf(px2, px2, fmaf(py2, py2, pz2 * pz2));
    const float ps3 = fmaf(px3, px3, fmaf(py3, py3, pz3 * pz3));

    float cub0 = 0.f, cub1 = 0.f, cub2 = 0.f, cub3 = 0.f;
    float am0 = 0.f, am1 = 0.f, am2 = 0.f, am3 = 0.f;

    if (q == 0) {
        // superquadric samples (1 per thread)
        {
            const float e1 = shape[bp * 2 + 0];
            const float e2 = shape[bp * 2 + 1];
            float eta = etas[bp * SS + tid];
            float omg = omegas[bp * SS + tid];
            eta = (eta == 0.f) ? 1e-6f : eta;
            omg = (omg == 0.f) ? 1e-6f : omg;
            float ce = cosf(eta), se = sinf(eta);
            float co = cosf(omg), so = sinf(omg);
            float fce = fexp_f(ce, e1);
            float x = fix_f(sc0 * fce * fexp_f(co, e2));
            float y = fix_f(sc1 * fce * fexp_f(so, e2));
            float z = fix_f(sc2 * fexp_f(se, e1));
            float xsq = fmaf(x, x, fmaf(y, y, z * z));
            Xs[tid] = make_float4(-2.f * x, -2.f * y, -2.f * z, xsq);
        }
        // stage points for pass B
        Pts[pid * 4 + 0] = make_float4(px0, py0, pz0, ps0);
        Pts[pid * 4 + 1] = make_float4(px1, py1, pz1, ps1);
        Pts[pid * 4 + 2] = make_float4(px2, py2, pz2, ps2);
        Pts[pid * 4 + 3] = make_float4(px3, py3, pz3, ps3);
        // cuboid terms (normals used once; only half-0 loads them)
        const float4* nr4 = (const float4*)(nrm + ((size_t)bp * NN + n0) * 3);
        const float4 h0 = nr4[pid * 3 + 0];
        const float4 h1 = nr4[pid * 3 + 1];
        const float4 h2 = nr4[pid * 3 + 2];
        cub0 = cub_dist(px0, py0, pz0, h0.x, h0.y, h0.z, sc0, sc1, sc2);
        cub1 = cub_dist(px1, py1, pz1, h0.w, h1.x, h1.y, sc0, sc1, sc2);
        cub2 = cub_dist(px2, py2, pz2, h1.z, h1.w, h2.x, sc0, sc1, sc2);
        cub3 = cub_dist(px3, py3, pz3, h2.y, h2.z, h2.w, sc0, sc1, sc2);
        const size_t abase = ((size_t)b * NN + n0 + pid * 4) * PP + p;
        am0 = assign[abase + 0 * PP];
        am1 = assign[abase + 1 * PP];
        am2 = assign[abase + 2 * PP];
        am3 = assign[abase + 3 * PP];
    }
    __syncthreads();

    // ---- Pass A: min over this half's 64 s for 4 points (d_eff = |x|^2-2x.p) ----
    {
        const int sb = q * 64;
        float m0 = FINF, m1 = FINF, m2 = FINF, m3 = FINF;
        #pragma unroll 4
        for (int s = 0; s < 64; s += 2) {
            float4 xa = Xs[sb + s];
            float4 xb = Xs[sb + s + 1];
            float d;
            d = fmaf(xa.x, px0, fmaf(xa.y, py0, fmaf(xa.z, pz0, xa.w))); m0 = fminf(m0, d);
            d = fmaf(xa.x, px1, fmaf(xa.y, py1, fmaf(xa.z, pz1, xa.w))); m1 = fminf(m1, d);
            d = fmaf(xa.x, px2, fmaf(xa.y, py2, fmaf(xa.z, pz2, xa.w))); m2 = fminf(m2, d);
            d = fmaf(xa.x, px3, fmaf(xa.y, py3, fmaf(xa.z, pz3, xa.w))); m3 = fminf(m3, d);
            d = fmaf(xb.x, px0, fmaf(xb.y, py0, fmaf(xb.z, pz0, xb.w))); m0 = fminf(m0, d);
            d = fmaf(xb.x, px1, fmaf(xb.y, py1, fmaf(xb.z, pz1, xb.w))); m1 = fminf(m1, d);
            d = fmaf(xb.x, px2, fmaf(xb.y, py2, fmaf(xb.z, pz2, xb.w))); m2 = fminf(m2, d);
            d = fmaf(xb.x, px3, fmaf(xb.y, py3, fmaf(xb.z, pz3, xb.w))); m3 = fminf(m3, d);
        }
        dmin2[q][pid] = make_float4(m0, m1, m2, m3);
    }
    __syncthreads();

    // ---- half-0: combine s-halves, weight, wave-sum scalars ----
    if (q == 0) {
        float4 a = dmin2[0][pid];
        float4 c = dmin2[1][pid];
        float d0 = fminf(a.x, c.x) + ps0;
        float d1 = fminf(a.y, c.y) + ps1;
        float d2 = fminf(a.z, c.z) + ps2;
        float d3 = fminf(a.w, c.w) + ps3;
        float acc_pcl = d0 * am0 + d1 * am1 + d2 * am2 + d3 * am3;
        float acc_cub = cub0 * am0 + cub1 * am1 + cub2 * am2 + cub3 * am3;
        float acc_am  = am0 + am1 + am2 + am3;
        float s0 = wave_sum(acc_pcl);
        float s1 = wave_sum(acc_cub);
        float s2 = wave_sum(acc_am);
        const int lane_ = tid & 63, wave = tid >> 6;   // wave 0 or 1
        if (lane_ == 0) {
            wsum[wave * 3 + 0] = s0;
            wsum[wave * 3 + 1] = s1;
            wsum[wave * 3 + 2] = s2;
        }
    }

    // ---- Pass B: 4 s/thread, 8 point-replicas of 64 points each ----
    {
        const int rep = tid >> 5;     // 0..7
        const int sb  = tid & 31;
        const float4 x0 = Xs[sb];
        const float4 x1 = Xs[sb + 32];
        const float4 x2 = Xs[sb + 64];
        const float4 x3 = Xs[sb + 96];
        const int nb = rep * 64;
        float r0 = FINF, r1 = FINF, r2 = FINF, r3 = FINF;
        #pragma unroll 4
        for (int n = 0; n < 64; n += 2) {
            float4 pa = Pts[nb + n];
            float4 pb = Pts[nb + n + 1];
            float d;
            d = fmaf(x0.x, pa.x, fmaf(x0.y, pa.y, fmaf(x0.z, pa.z, pa.w))); r0 = fminf(r0, d);
            d = fmaf(x1.x, pa.x, fmaf(x1.y, pa.y, fmaf(x1.z, pa.z, pa.w))); r1 = fminf(r1, d);
            d = fmaf(x2.x, pa.x, fmaf(x2.y, pa.y, fmaf(x2.z, pa.z, pa.w))); r2 = fminf(r2, d);
            d = fmaf(x3.x, pa.x, fmaf(x3.y, pa.y, fmaf(x3.z, pa.z, pa.w))); r3 = fminf(r3, d);
            d = fmaf(x0.x, pb.x, fmaf(x0.y, pb.y, fmaf(x0.z, pb.z, pb.w))); r0 = fminf(r0, d);
            d = fmaf(x1.x, pb.x, fmaf(x1.y, pb.y, fmaf(x1.z, pb.z, pb.w))); r1 = fminf(r1, d);
            d = fmaf(x2.x, pb.x, fmaf(x2.y, pb.y, fmaf(x2.z, pb.z, pb.w))); r2 = fminf(r2, d);
            d = fmaf(x3.x, pb.x, fmaf(x3.y, pb.y, fmaf(x3.z, pb.z, pb.w))); r3 = fminf(r3, d);
        }
        red[rep * SS + sb +  0] = r0;   // d_eff2 = |p|^2 - 2x.p
        red[rep * SS + sb + 32] = r1;
        red[rep * SS + sb + 64] = r2;
        red[rep * SS + sb + 96] = r3;
    }
    __syncthreads();

    // ---- publish per-(bp,s) split min into OWN slot + scalars (no contention) ----
    if (tid < SS) {
        float m = red[tid];
        #pragma unroll
        for (int r = 1; r < 8; ++r) m = fminf(m, red[r * SS + tid]);
        astore(ws + SMIN_F + ((bp * SS + tid) << 3) + split, m + Xs[tid].w);
    }
    if (tid == 0) {
        float* sc = ws + SCAL_F + (bp * NSPLIT + split) * 4;
        astore(sc + 0, wsum[0] + wsum[3]);
        astore(sc + 1, wsum[1] + wsum[4]);
        astore(sc + 2, wsum[2] + wsum[5]);
    }

    // ---- per-bp handoff: 6th split-block of this bp reduces the bp ----
    __syncthreads();
    if (tid == 0) {
        asm volatile("s_waitcnt vmcnt(0)" ::: "memory");   // stores ack'd at coherent point
        s_cnt1 = __hip_atomic_fetch_add((unsigned*)(ws + CNT_F) + bp, 1u,
                                        __ATOMIC_RELAXED, __HIP_MEMORY_SCOPE_AGENT);
    }
    __syncthreads();
    if (s_cnt1 != (unsigned)(NSPLIT - 1)) return;

    // ======== per-bp finisher (96 blocks, overlapped with other compute) ========
    {
        const int lane = tid & 63;
        if (tid < SS) {                       // waves 0,1: s = tid
            const float* mb = ws + SMIN_F + ((bp * SS + tid) << 3);
            const float v0 = aload(mb + 0), v1 = aload(mb + 1), v2 = aload(mb + 2);
            const float v3 = aload(mb + 3), v4 = aload(mb + 4), v5 = aload(mb + 5);
            // exact round-0 fminf tree order over splits
            float m = fminf(fminf(fminf(v0, v1), fminf(v2, v3)), fminf(v4, v5));
            float sm = wave_sum(m);           // 64 consecutive s per wave (same grouping)
            if (lane == 0) wsum[tid >> 6] = sm;
        } else if (tid < 128 + 18) {          // wave 2: 18 scalar loads in parallel
            const int j = tid - 128, sp = j / 3, c = j % 3;
            red[600 + j] = aload(ws + SCAL_F + (bp * NSPLIT + sp) * 4 + c);
        }
        __syncthreads();
        if (tid == 0) {
            const float prim = wsum[0] + wsum[1];      // fixed order (== 2-addend atomic)
            float pcl = 0.f, cubv = 0.f, cs = 0.f;
            #pragma unroll
            for (int sp = 0; sp < NSPLIT; ++sp) {      // same split-order sum as before
                pcl  += red[600 + sp * 3 + 0];
                cubv += red[600 + sp * 3 + 1];
                cs   += red[600 + sp * 3 + 2];
            }
            float* r4 = ws + BPRES_F + bp * 4;
            astore(r4 + 0, prim);
            astore(r4 + 1, pcl);
            astore(r4 + 2, cubv);
            astore(r4 + 3, cs);
            asm volatile("s_waitcnt vmcnt(0)" ::: "memory");
            s_cnt2 = __hip_atomic_fetch_add((unsigned*)(ws + CNT_F) + 96, 1u,
                                            __ATOMIC_RELAXED, __HIP_MEMORY_SCOPE_AGENT);
        }
        __syncthreads();
        if (s_cnt2 != 95u) return;
    }

    // ======== global final (single block, single latency round) ========
    // red[0..95]=prim, [96..191]=pcl, [192..287]=cub, [288..383]=bce,
    // [384..479]=e, [480..575]=sq
    if (tid < 96) {
        const float* r4 = ws + BPRES_F + tid * 4;
        const float prim = aload(r4 + 0);
        const float pcl  = aload(r4 + 1);
        const float cubv = aload(r4 + 2);
        const float cs   = aload(r4 + 3);
        const float e  = exist[tid];
        const float gt = (cs > 24.0f) ? 1.f : 0.f;
        red[  0 + tid] = prim;
        red[ 96 + tid] = pcl;
        red[192 + tid] = cubv;
        red[288 + tid] = gt * logf(e) + (1.f - gt) * log1pf(-e);
        red[384 + tid] = e;
        red[480 + tid] = sqrtf(cs / (float)NN + 0.01f);
    }
    __syncthreads();

    if (tid == 0) {
        float pcl_sum = 0.f, cub_sum = 0.f, bce_sum = 0.f, prim_loss = 0.f, sps = 0.f;
        #pragma unroll
        for (int b_ = 0; b_ < BB; ++b_) {
            float pe = 0.f, ee = 0.f, sq = 0.f;
            #pragma unroll
            for (int p_ = 0; p_ < PP; ++p_) {
                const int i = b_ * PP + p_;
                pcl_sum += red[ 96 + i];
                cub_sum += red[192 + i];
                bce_sum += red[288 + i];
                pe += (red[i] / (float)SS) * red[384 + i];
                ee += red[384 + i];
                sq += red[480 + i];
            }
            prim_loss += pe / (ee + 1e-6f);
            float mb = sq / (float)PP;
            sps += mb * mb;
        }
        prim_loss /= (float)BB;
        sps       /= (float)BB;
        float pcl_loss = pcl_sum / (float)(BB * NN);
        float cubf     = cub_sum / (float)(BB * NN);
        float bce      = -bce_sum / (float)(BB * PP);
        out[0] = 0.1f * cubf + 1.0f * (pcl_loss + prim_loss) + 0.01f * bce + 0.01f * sps;
    }
}

extern "C" void kernel_launch(void* const* d_in, const int* in_sizes, int n_in,
                              void* d_out, int out_size, void* d_ws, size_t ws_size,
                              hipStream_t stream) {
    const float* pc     = (const float*)d_in[0];
    const float* nrm    = (const float*)d_in[1];
    const float* scale  = (const float*)d_in[2];
    const float* shape  = (const float*)d_in[3];
    const float* exist  = (const float*)d_in[4];
    const float* assign = (const float*)d_in[5];
    const float* etas   = (const float*)d_in[6];
    const float* omegas = (const float*)d_in[7];
    float* ws  = (float*)d_ws;
    float* out = (float*)d_out;

    // zero the 97 counters (ws is poisoned by the harness each iteration)
    superdec_init<<<1, 128, 0, stream>>>(ws);

    superdec_fused<<<GRID, 256, 0, stream>>>(
        pc, nrm, scale, shape, exist, assign, etas, omegas, ws, out);
}